// Round 1
// 451.747 us; speedup vs baseline: 1.4310x; 1.4310x over previous
//
#include <hip/hip_runtime.h>

namespace {

constexpr int P   = 361;
constexpr int Fd  = 20;
constexpr int BPc = 256 * P;        // 92416 sites
constexpr int NG  = BPc / 32;       // 2888 site-groups per f
constexpr int GPW = 19;             // groups per wave-stream
constexpr int GX  = (NG / GPW) / 4; // 38 blocks.x (4 waves/block)

constexpr int OTS = 36;             // out-tile row stride in floats (144B, 16B-aligned)

typedef __bf16 bf16x8 __attribute__((ext_vector_type(8)));
typedef float  f32x16 __attribute__((ext_vector_type(16)));

__device__ __forceinline__ float gelu_f(float x) {
    const float u  = x * 0.70710678118654752440f;
    const float au = __builtin_fabsf(u);
    const float t  = __builtin_amdgcn_rcpf(__builtin_fmaf(0.3275911f, au, 1.0f));
    float poly = __builtin_fmaf(1.061405429f, t, -1.453152027f);
    poly = __builtin_fmaf(poly, t, 1.421413741f);
    poly = __builtin_fmaf(poly, t, -0.284496736f);
    poly = __builtin_fmaf(poly, t, 0.254829592f);
    poly *= t;
    const float e2 = __builtin_amdgcn_exp2f(-u * u * 1.4426950408889634f);
    const float erf_abs = __builtin_fmaf(-poly, e2, 1.0f);
    const float erf_u = __builtin_copysignf(erf_abs, u);
    return 0.5f * x * (1.0f + erf_u);
}

// round-to-nearest-even bf16 bits
__device__ __forceinline__ unsigned rne_bf16(float v) {
    unsigned b = __builtin_bit_cast(unsigned, v);
    return (b + 0x7FFFu + ((b >> 16) & 1u)) >> 16;
}

// split v ~= hi + lo, both bf16 (16-bit patterns returned in low 16 bits)
__device__ __forceinline__ void split2(float v, unsigned& h, unsigned& l) {
    h = rne_bf16(v);
    l = rne_bf16(v - __builtin_bit_cast(float, h << 16));
}

__device__ __forceinline__ bf16x8 as_bf8(uint4 u) {
    return __builtin_bit_cast(bf16x8, u);
}

// 3-MFMA bf16x3 product: acc += A * B with A = (ah+al) from LDS frags,
// B = (bh+bl) in registers. Drops al*bl (~2^-18 rel).
__device__ __forceinline__ f32x16 mfma3(const uint4* lf, int lane,
                                        uint4 bh, uint4 bl, f32x16 acc) {
    bf16x8 ah = as_bf8(lf[lane]);
    bf16x8 al = as_bf8(lf[64 + lane]);
    acc = __builtin_amdgcn_mfma_f32_32x32x16_bf16(ah, as_bf8(bh), acc, 0, 0, 0);
    acc = __builtin_amdgcn_mfma_f32_32x32x16_bf16(ah, as_bf8(bl), acc, 0, 0, 0);
    acc = __builtin_amdgcn_mfma_f32_32x32x16_bf16(al, as_bf8(bh), acc, 0, 0, 0);
    return acc;
}

// read per-lane bias (accumulator init) from LDS: layout [half*16 + q*4 + e]
// holds bias[row = e + 8q + 4*half], matching C/D row = (r&3)+8*(r>>2)+4*half.
__device__ __forceinline__ f32x16 bias_acc(const float* lb, int half) {
    f32x16 a;
    const float4* p = (const float4*)(lb + half * 16);
#pragma unroll
    for (int q = 0; q < 4; ++q) {
        float4 v = p[q];
        a[4*q+0] = v.x; a[4*q+1] = v.y; a[4*q+2] = v.z; a[4*q+3] = v.w;
    }
    return a;
}

__device__ __forceinline__ void gelu16(f32x16& c) {
#pragma unroll
    for (int e = 0; e < 16; ++e) c[e] = gelu_f(c[e]);
}

// C/D-layout (32 feats x 32 sites) -> two B-fragments (k=0..15, k=16..31),
// hi+lo bf16. C/D: lane holds col n=lane&31, rows (r&3)+8*(r>>2)+4*half.
// B-frag: lane holds n=lane&31, k=(lane>>5)*8+j. Requires a lane^32 half-swap.
__device__ __forceinline__ void transform_cd(const f32x16 c, int lane, int half,
                                             uint4* H, uint4* L) {
    unsigned hd[8], ld[8];
#pragma unroll
    for (int q = 0; q < 4; ++q) {
        unsigned h0, l0, h1, l1, h2, l2, h3, l3;
        split2(c[4*q+0], h0, l0);
        split2(c[4*q+1], h1, l1);
        split2(c[4*q+2], h2, l2);
        split2(c[4*q+3], h3, l3);
        hd[2*q]   = h0 | (h1 << 16);
        hd[2*q+1] = h2 | (h3 << 16);
        ld[2*q]   = l0 | (l1 << 16);
        ld[2*q+1] = l2 | (l3 << 16);
    }
#pragma unroll
    for (int cix = 0; cix < 2; ++cix) {
        const int qlo = 2*cix, qhi = 2*cix + 1;
#pragma unroll
        for (int pr = 0; pr < 2; ++pr) {
            const unsigned* d = pr ? ld : hd;
            unsigned k0 = half ? d[2*qhi]   : d[2*qlo];
            unsigned k1 = half ? d[2*qhi+1] : d[2*qlo+1];
            unsigned s0 = half ? d[2*qlo]   : d[2*qhi];
            unsigned s1 = half ? d[2*qlo+1] : d[2*qhi+1];
            unsigned r0 = (unsigned)__shfl((int)s0, lane ^ 32, 64);
            unsigned r1 = (unsigned)__shfl((int)s1, lane ^ 32, 64);
            uint4 v;
            v.x = half ? r0 : k0;
            v.y = half ? r1 : k1;
            v.z = half ? k0 : r0;
            v.w = half ? k1 : r1;
            (pr ? L : H)[cix] = v;
        }
    }
}

__global__ __launch_bounds__(256, 3) void dcp_mfma_kernel(
    const float* __restrict__ x,
    const float* __restrict__ Wr1, const float* __restrict__ br1,
    const float* __restrict__ Wr2, const float* __restrict__ br2,
    const float* __restrict__ Wr3, const float* __restrict__ br3,
    const float* __restrict__ Wi1, const float* __restrict__ bi1,
    const float* __restrict__ Wi2, const float* __restrict__ bi2,
    const float* __restrict__ Wi3, const float* __restrict__ bi3,
    const float* __restrict__ Wf1, const float* __restrict__ bf1,
    const float* __restrict__ Wf2, const float* __restrict__ bf2,
    float* __restrict__ out)
{
    // 12 weight A-chunks x {hi,lo}: frag fi=2*chunk+prec, per-lane uint4.
    __shared__ uint4 lfrag[24][64];
    __shared__ __align__(16) float lbias[6][32];
    __shared__ float l1w[2][2][16];   // [branch][0=w,1=b][k]
    // per-wave out-staging tile: 32 sites x 32 feats, row stride OTS floats
    __shared__ __align__(16) float lout[4][32 * OTS];

    const int f   = blockIdx.y;
    const int tid = threadIdx.x;

    // ---------- setup: stage weight A-fragments (bf16 hi/lo) into LDS ----------
    // A[m][k] = W[f][k0+k][m]; lane l: m=l&31, k=(l>>5)*8+j.
    for (int s = tid; s < 12 * 64; s += 256) {
        const int chunk = s >> 6;
        const int l     = s & 63;
        const int m     = l & 31;
        const int kb    = (l >> 5) * 8;
        const float* base; int k0;
        switch (chunk) {
            case 0:  base = Wr2 + f * 512;  k0 = 0;  break;
            case 1:  base = Wi2 + f * 512;  k0 = 0;  break;
            case 2:  base = Wr3 + f * 1024; k0 = 0;  break;
            case 3:  base = Wr3 + f * 1024; k0 = 16; break;
            case 4:  base = Wi3 + f * 1024; k0 = 0;  break;
            case 5:  base = Wi3 + f * 1024; k0 = 16; break;
            case 6:  base = Wf1 + f * 2048; k0 = 0;  break;
            case 7:  base = Wf1 + f * 2048; k0 = 16; break;
            case 8:  base = Wf1 + f * 2048; k0 = 32; break;
            case 9:  base = Wf1 + f * 2048; k0 = 48; break;
            case 10: base = Wf2 + f * 1024; k0 = 0;  break;
            default: base = Wf2 + f * 1024; k0 = 16; break;
        }
        unsigned hs[8], ls[8];
#pragma unroll
        for (int j = 0; j < 8; ++j) {
            split2(base[(k0 + kb + j) * 32 + m], hs[j], ls[j]);
        }
        uint4 hv, lv;
        hv.x = hs[0] | (hs[1] << 16); hv.y = hs[2] | (hs[3] << 16);
        hv.z = hs[4] | (hs[5] << 16); hv.w = hs[6] | (hs[7] << 16);
        lv.x = ls[0] | (ls[1] << 16); lv.y = ls[2] | (ls[3] << 16);
        lv.z = ls[4] | (ls[5] << 16); lv.w = ls[6] | (ls[7] << 16);
        lfrag[2 * chunk + 0][l] = hv;
        lfrag[2 * chunk + 1][l] = lv;
    }
    // biases, rearranged to C/D reg order per lane-half
    if (tid < 192) {
        const int set = tid >> 5, i = tid & 31;
        const int row = (i & 3) + 8 * ((i >> 2) & 3) + 4 * (i >> 4);
        const float* bp;
        switch (set) {
            case 0: bp = br2; break; case 1: bp = bi2; break;
            case 2: bp = br3; break; case 3: bp = bi3; break;
            case 4: bp = bf1; break; default: bp = bf2; break;
        }
        lbias[set][i] = bp[f * 32 + row];
    }
    // layer-1 params
    if (tid < 64) {
        const int br = tid >> 5, rem = tid & 31, ty = rem >> 4, k = rem & 15;
        const float* p = br ? (ty ? bi1 : Wi1) : (ty ? br1 : Wr1);
        l1w[br][ty][k] = p[f * 16 + k];
    }
    __syncthreads();

    const int lane    = tid & 63;
    const int wv      = tid >> 6;
    const int n       = lane & 31;
    const int half    = lane >> 5;
    const int kb      = half * 8;
    const int wstream = blockIdx.x * 4 + wv;

    float* lw = &lout[wv][0];
    const int s_lo = lane >> 3;   // 0..7: which site of the 8-site store slab
    const int cpos = lane & 7;    // which 16B chunk of the site's 128B line

    for (int t = 0; t < GPW; ++t) {
        const int g    = wstream * GPW + t;
        const int site = g * 32 + n;
        const float2 xv = *(const float2*)(x + ((size_t)site * Fd + f) * 2);

        // ---- L1 (K=1, on VALU), directly in B-fragment layout ----
        uint4 b1h[2], b1l[2];
#pragma unroll
        for (int br = 0; br < 2; ++br) {
            const float xs = br ? xv.y : xv.x;
            unsigned hs[8], ls[8];
#pragma unroll
            for (int j = 0; j < 8; ++j) {
                float h = gelu_f(fmaf(xs, l1w[br][0][kb + j], l1w[br][1][kb + j]));
                split2(h, hs[j], ls[j]);
            }
            uint4 hv, lv;
            hv.x = hs[0] | (hs[1] << 16); hv.y = hs[2] | (hs[3] << 16);
            hv.z = hs[4] | (hs[5] << 16); hv.w = hs[6] | (hs[7] << 16);
            lv.x = ls[0] | (ls[1] << 16); lv.y = ls[2] | (ls[3] << 16);
            lv.z = ls[4] | (ls[5] << 16); lv.w = ls[6] | (ls[7] << 16);
            b1h[br] = hv; b1l[br] = lv;
        }

        // ---- L2: 16 -> 32, gelu ----
        f32x16 cr = bias_acc(lbias[0], half);
        f32x16 ci = bias_acc(lbias[1], half);
        cr = mfma3(&lfrag[0][0], lane, b1h[0], b1l[0], cr);
        ci = mfma3(&lfrag[2][0], lane, b1h[1], b1l[1], ci);
        gelu16(cr); gelu16(ci);
        uint4 b2h[2][2], b2l[2][2];
        transform_cd(cr, lane, half, b2h[0], b2l[0]);
        transform_cd(ci, lane, half, b2h[1], b2l[1]);

        // ---- L3: 32 -> 32, linear ----
        f32x16 ro = bias_acc(lbias[2], half);
        f32x16 io = bias_acc(lbias[3], half);
        ro = mfma3(&lfrag[4][0],  lane, b2h[0][0], b2l[0][0], ro);
        ro = mfma3(&lfrag[6][0],  lane, b2h[0][1], b2l[0][1], ro);
        io = mfma3(&lfrag[8][0],  lane, b2h[1][0], b2l[1][0], io);
        io = mfma3(&lfrag[10][0], lane, b2h[1][1], b2l[1][1], io);
        uint4 fh[4], fl[4];
        transform_cd(ro, lane, half, &fh[0], &fl[0]);   // F1 k = 0..31
        transform_cd(io, lane, half, &fh[2], &fl[2]);   // F1 k = 32..63

        // ---- F1: 64 -> 32, gelu ----
        f32x16 c1 = bias_acc(lbias[4], half);
        c1 = mfma3(&lfrag[12][0], lane, fh[0], fl[0], c1);
        c1 = mfma3(&lfrag[14][0], lane, fh[1], fl[1], c1);
        c1 = mfma3(&lfrag[16][0], lane, fh[2], fl[2], c1);
        c1 = mfma3(&lfrag[18][0], lane, fh[3], fl[3], c1);
        gelu16(c1);
        uint4 gh[2], gl[2];
        transform_cd(c1, lane, half, gh, gl);

        // ---- F2: 32 -> 32, gelu ----
        f32x16 c2 = bias_acc(lbias[5], half);
        c2 = mfma3(&lfrag[20][0], lane, gh[0], gl[0], c2);
        c2 = mfma3(&lfrag[22][0], lane, gh[1], gl[1], c2);
        gelu16(c2);

        // ---- store: stage through per-wave LDS tile, then write FULL
        // 128B lines (8 lanes x 16B per site) to kill partial-sector RMW ----
        // register layout: lane holds site n, feats {4*half + 8q + e}.
#pragma unroll
        for (int q = 0; q < 4; ++q) {
            *(float4*)(lw + n * OTS + q * 8 + 4 * half) =
                make_float4(c2[4*q+0], c2[4*q+1], c2[4*q+2], c2[4*q+3]);
        }
        // within-wave LDS write->read: drain LDS queue, fence compiler reorder
        asm volatile("s_waitcnt lgkmcnt(0)" ::: "memory");
        __builtin_amdgcn_sched_barrier(0);
#pragma unroll
        for (int it = 0; it < 4; ++it) {
            const int sl    = it * 8 + s_lo;           // site-local 0..31
            const int gsite = g * 32 + sl;
            float4 v = *(const float4*)(lw + sl * OTS + cpos * 4);
            *(float4*)(out + ((size_t)gsite * Fd + f) * 32 + cpos * 4) = v;
        }
    }
}

} // anonymous namespace

extern "C" void kernel_launch(void* const* d_in, const int* in_sizes, int n_in,
                              void* d_out, int out_size, void* d_ws, size_t ws_size,
                              hipStream_t stream)
{
    const float* x   = (const float*)d_in[0];
    const float* Wr1 = (const float*)d_in[1];
    const float* br1 = (const float*)d_in[2];
    const float* Wr2 = (const float*)d_in[3];
    const float* br2 = (const float*)d_in[4];
    const float* Wr3 = (const float*)d_in[5];
    const float* br3 = (const float*)d_in[6];
    const float* Wi1 = (const float*)d_in[7];
    const float* bi1 = (const float*)d_in[8];
    const float* Wi2 = (const float*)d_in[9];
    const float* bi2 = (const float*)d_in[10];
    const float* Wi3 = (const float*)d_in[11];
    const float* bi3 = (const float*)d_in[12];
    const float* Wf1 = (const float*)d_in[13];
    const float* bf1 = (const float*)d_in[14];
    const float* Wf2 = (const float*)d_in[15];
    const float* bf2 = (const float*)d_in[16];
    float* out = (float*)d_out;

    dim3 grid(GX, Fd, 1);
    dim3 block(256, 1, 1);
    hipLaunchKernelGGL(dcp_mfma_kernel, grid, block, 0, stream,
                       x, Wr1, br1, Wr2, br2, Wr3, br3,
                       Wi1, bi1, Wi2, bi2, Wi3, bi3,
                       Wf1, bf1, Wf2, bf2, out);
}

// Round 2
// 401.307 us; speedup vs baseline: 1.6109x; 1.1257x over previous
//
#include <hip/hip_runtime.h>

namespace {

constexpr int P   = 361;
constexpr int Fd  = 20;
constexpr int BPc = 256 * P;        // 92416 sites
constexpr int NG  = BPc / 32;       // 2888 site-groups per f
constexpr int GPW = 19;             // groups per wave-stream
constexpr int GX  = (NG / GPW) / 4; // 38 blocks.x (4 waves/block)

constexpr int OTS = 36;             // out-tile row stride in floats (144B, 16B-aligned)

typedef __bf16 bf16x8 __attribute__((ext_vector_type(8)));
typedef __bf16 bf16x2 __attribute__((ext_vector_type(2)));
typedef float  f32x2v __attribute__((ext_vector_type(2)));
typedef float  f32x16 __attribute__((ext_vector_type(16)));

__device__ __forceinline__ float gelu_f(float x) {
    const float u  = x * 0.70710678118654752440f;
    const float au = __builtin_fabsf(u);
    const float t  = __builtin_amdgcn_rcpf(__builtin_fmaf(0.3275911f, au, 1.0f));
    float poly = __builtin_fmaf(1.061405429f, t, -1.453152027f);
    poly = __builtin_fmaf(poly, t, 1.421413741f);
    poly = __builtin_fmaf(poly, t, -0.284496736f);
    poly = __builtin_fmaf(poly, t, 0.254829592f);
    poly *= t;
    const float e2 = __builtin_amdgcn_exp2f(-u * u * 1.4426950408889634f);
    const float erf_abs = __builtin_fmaf(-poly, e2, 1.0f);
    const float erf_u = __builtin_copysignf(erf_abs, u);
    return 0.5f * x * (1.0f + erf_u);
}

// (v0,v1) -> packed hi-bf16 word + packed lo-bf16 word, RNE, via v_cvt_pk_bf16_f32
__device__ __forceinline__ void split_pk(float v0, float v1, unsigned& hw, unsigned& lw) {
    f32x2v vv = {v0, v1};
    bf16x2 hv = __builtin_convertvector(vv, bf16x2);
    unsigned hp = __builtin_bit_cast(unsigned, hv);
    float r0 = __builtin_bit_cast(float, hp << 16);
    float r1 = __builtin_bit_cast(float, hp & 0xffff0000u);
    f32x2v rv = {v0 - r0, v1 - r1};
    bf16x2 lv = __builtin_convertvector(rv, bf16x2);
    hw = hp;
    lw = __builtin_bit_cast(unsigned, lv);
}

__device__ __forceinline__ bf16x8 as_bf8(uint4 u) {
    return __builtin_bit_cast(bf16x8, u);
}

// 3-MFMA bf16x3 product: acc += A * B with A = (ah+al) from LDS frags,
// B = (bh+bl) in registers. Drops al*bl (~2^-18 rel).
__device__ __forceinline__ f32x16 mfma3(const uint4* lf, int lane,
                                        uint4 bh, uint4 bl, f32x16 acc) {
    bf16x8 ah = as_bf8(lf[lane]);
    bf16x8 al = as_bf8(lf[64 + lane]);
    acc = __builtin_amdgcn_mfma_f32_32x32x16_bf16(ah, as_bf8(bh), acc, 0, 0, 0);
    acc = __builtin_amdgcn_mfma_f32_32x32x16_bf16(ah, as_bf8(bl), acc, 0, 0, 0);
    acc = __builtin_amdgcn_mfma_f32_32x32x16_bf16(al, as_bf8(bh), acc, 0, 0, 0);
    return acc;
}

// read per-lane bias (accumulator init) from LDS: layout [half*16 + q*4 + e]
// holds bias[row = e + 8q + 4*half], matching C/D row = (r&3)+8*(r>>2)+4*half.
__device__ __forceinline__ f32x16 bias_acc(const float* lb, int half) {
    f32x16 a;
    const float4* p = (const float4*)(lb + half * 16);
#pragma unroll
    for (int q = 0; q < 4; ++q) {
        float4 v = p[q];
        a[4*q+0] = v.x; a[4*q+1] = v.y; a[4*q+2] = v.z; a[4*q+3] = v.w;
    }
    return a;
}

__device__ __forceinline__ void gelu16(f32x16& c) {
#pragma unroll
    for (int e = 0; e < 16; ++e) c[e] = gelu_f(c[e]);
}

// C/D-layout (32 feats x 32 sites) -> two B-fragments (k=0..15, k=16..31),
// hi+lo bf16. C/D: lane holds col n=lane&31, rows (r&3)+8*(r>>2)+4*half.
// B-frag: lane holds n=lane&31, k=(lane>>5)*8+j.
// The half exchange is exactly v_permlane32_swap:
//   swap(A,B): A' = {A_lo, B_lo}, B' = {A_hi, B_hi}
//   v.x,v.z = swap(d[4c+0], d[4c+2]); v.y,v.w = swap(d[4c+1], d[4c+3]).
__device__ __forceinline__ void transform_cd(const f32x16 c, uint4* H, uint4* L) {
    unsigned hd[8], ld[8];
#pragma unroll
    for (int q = 0; q < 4; ++q) {
        split_pk(c[4*q+0], c[4*q+1], hd[2*q],   ld[2*q]);
        split_pk(c[4*q+2], c[4*q+3], hd[2*q+1], ld[2*q+1]);
    }
#pragma unroll
    for (int pr = 0; pr < 2; ++pr) {
        unsigned* d = pr ? ld : hd;
#pragma unroll
        for (int cix = 0; cix < 2; ++cix) {
            unsigned a0 = d[4*cix+0], b0 = d[4*cix+2];
            unsigned a1 = d[4*cix+1], b1 = d[4*cix+3];
            asm("v_permlane32_swap_b32 %0, %1" : "+v"(a0), "+v"(b0));
            asm("v_permlane32_swap_b32 %0, %1" : "+v"(a1), "+v"(b1));
            uint4 v;
            v.x = a0; v.y = a1; v.z = b0; v.w = b1;
            (pr ? L : H)[cix] = v;
        }
    }
}

__global__ __launch_bounds__(256, 3) void dcp_mfma_kernel(
    const float* __restrict__ x,
    const float* __restrict__ Wr1, const float* __restrict__ br1,
    const float* __restrict__ Wr2, const float* __restrict__ br2,
    const float* __restrict__ Wr3, const float* __restrict__ br3,
    const float* __restrict__ Wi1, const float* __restrict__ bi1,
    const float* __restrict__ Wi2, const float* __restrict__ bi2,
    const float* __restrict__ Wi3, const float* __restrict__ bi3,
    const float* __restrict__ Wf1, const float* __restrict__ bf1,
    const float* __restrict__ Wf2, const float* __restrict__ bf2,
    float* __restrict__ out)
{
    // 12 weight A-chunks x {hi,lo}: frag fi=2*chunk+prec, per-lane uint4.
    __shared__ uint4 lfrag[24][64];
    __shared__ __align__(16) float lbias[6][32];
    __shared__ float l1w[2][2][16];   // [branch][0=w,1=b][k]
    // per-wave out-staging tile: 32 sites x 32 feats, row stride OTS floats
    __shared__ __align__(16) float lout[4][32 * OTS];

    const int f   = blockIdx.y;
    const int tid = threadIdx.x;

    // ---------- setup: stage weight A-fragments (bf16 hi/lo) into LDS ----------
    // A[m][k] = W[f][k0+k][m]; lane l: m=l&31, k=(l>>5)*8+j.
    for (int s = tid; s < 12 * 64; s += 256) {
        const int chunk = s >> 6;
        const int l     = s & 63;
        const int m     = l & 31;
        const int kb    = (l >> 5) * 8;
        const float* base; int k0;
        switch (chunk) {
            case 0:  base = Wr2 + f * 512;  k0 = 0;  break;
            case 1:  base = Wi2 + f * 512;  k0 = 0;  break;
            case 2:  base = Wr3 + f * 1024; k0 = 0;  break;
            case 3:  base = Wr3 + f * 1024; k0 = 16; break;
            case 4:  base = Wi3 + f * 1024; k0 = 0;  break;
            case 5:  base = Wi3 + f * 1024; k0 = 16; break;
            case 6:  base = Wf1 + f * 2048; k0 = 0;  break;
            case 7:  base = Wf1 + f * 2048; k0 = 16; break;
            case 8:  base = Wf1 + f * 2048; k0 = 32; break;
            case 9:  base = Wf1 + f * 2048; k0 = 48; break;
            case 10: base = Wf2 + f * 1024; k0 = 0;  break;
            default: base = Wf2 + f * 1024; k0 = 16; break;
        }
        uint4 hv, lv;
        split_pk(base[(k0 + kb + 0) * 32 + m], base[(k0 + kb + 1) * 32 + m], hv.x, lv.x);
        split_pk(base[(k0 + kb + 2) * 32 + m], base[(k0 + kb + 3) * 32 + m], hv.y, lv.y);
        split_pk(base[(k0 + kb + 4) * 32 + m], base[(k0 + kb + 5) * 32 + m], hv.z, lv.z);
        split_pk(base[(k0 + kb + 6) * 32 + m], base[(k0 + kb + 7) * 32 + m], hv.w, lv.w);
        lfrag[2 * chunk + 0][l] = hv;
        lfrag[2 * chunk + 1][l] = lv;
    }
    // biases, rearranged to C/D reg order per lane-half
    if (tid < 192) {
        const int set = tid >> 5, i = tid & 31;
        const int row = (i & 3) + 8 * ((i >> 2) & 3) + 4 * (i >> 4);
        const float* bp;
        switch (set) {
            case 0: bp = br2; break; case 1: bp = bi2; break;
            case 2: bp = br3; break; case 3: bp = bi3; break;
            case 4: bp = bf1; break; default: bp = bf2; break;
        }
        lbias[set][i] = bp[f * 32 + row];
    }
    // layer-1 params
    if (tid < 64) {
        const int br = tid >> 5, rem = tid & 31, ty = rem >> 4, k = rem & 15;
        const float* p = br ? (ty ? bi1 : Wi1) : (ty ? br1 : Wr1);
        l1w[br][ty][k] = p[f * 16 + k];
    }
    __syncthreads();

    const int lane    = tid & 63;
    const int wv      = tid >> 6;
    const int n       = lane & 31;
    const int half    = lane >> 5;
    const int kb      = half * 8;
    const int wstream = blockIdx.x * 4 + wv;

    float* lw = &lout[wv][0];
    const int s_lo = lane >> 3;   // 0..7: which site of the 8-site store slab
    const int cpos = lane & 7;    // which 16B chunk of the site's 128B line

    for (int t = 0; t < GPW; ++t) {
        const int g    = wstream * GPW + t;
        const int site = g * 32 + n;
        const float2 xv = *(const float2*)(x + ((size_t)site * Fd + f) * 2);

        // ---- L1 (K=1, on VALU), directly in B-fragment layout ----
        uint4 b1h[2], b1l[2];
#pragma unroll
        for (int br = 0; br < 2; ++br) {
            const float xs = br ? xv.y : xv.x;
            float h[8];
#pragma unroll
            for (int j = 0; j < 8; ++j) {
                h[j] = gelu_f(fmaf(xs, l1w[br][0][kb + j], l1w[br][1][kb + j]));
            }
            uint4 hv, lv;
            split_pk(h[0], h[1], hv.x, lv.x);
            split_pk(h[2], h[3], hv.y, lv.y);
            split_pk(h[4], h[5], hv.z, lv.z);
            split_pk(h[6], h[7], hv.w, lv.w);
            b1h[br] = hv; b1l[br] = lv;
        }

        // ---- L2: 16 -> 32, gelu ----
        f32x16 cr = bias_acc(lbias[0], half);
        f32x16 ci = bias_acc(lbias[1], half);
        cr = mfma3(&lfrag[0][0], lane, b1h[0], b1l[0], cr);
        ci = mfma3(&lfrag[2][0], lane, b1h[1], b1l[1], ci);
        gelu16(cr); gelu16(ci);
        uint4 b2h[2][2], b2l[2][2];
        transform_cd(cr, b2h[0], b2l[0]);
        transform_cd(ci, b2h[1], b2l[1]);

        // ---- L3: 32 -> 32, linear ----
        f32x16 ro = bias_acc(lbias[2], half);
        f32x16 io = bias_acc(lbias[3], half);
        ro = mfma3(&lfrag[4][0],  lane, b2h[0][0], b2l[0][0], ro);
        ro = mfma3(&lfrag[6][0],  lane, b2h[0][1], b2l[0][1], ro);
        io = mfma3(&lfrag[8][0],  lane, b2h[1][0], b2l[1][0], io);
        io = mfma3(&lfrag[10][0], lane, b2h[1][1], b2l[1][1], io);
        uint4 fh[4], fl[4];
        transform_cd(ro, &fh[0], &fl[0]);   // F1 k = 0..31
        transform_cd(io, &fh[2], &fl[2]);   // F1 k = 32..63

        // ---- F1: 64 -> 32, gelu ----
        f32x16 c1 = bias_acc(lbias[4], half);
        c1 = mfma3(&lfrag[12][0], lane, fh[0], fl[0], c1);
        c1 = mfma3(&lfrag[14][0], lane, fh[1], fl[1], c1);
        c1 = mfma3(&lfrag[16][0], lane, fh[2], fl[2], c1);
        c1 = mfma3(&lfrag[18][0], lane, fh[3], fl[3], c1);
        gelu16(c1);
        uint4 gh[2], gl[2];
        transform_cd(c1, gh, gl);

        // ---- F2: 32 -> 32, gelu ----
        f32x16 c2 = bias_acc(lbias[5], half);
        c2 = mfma3(&lfrag[20][0], lane, gh[0], gl[0], c2);
        c2 = mfma3(&lfrag[22][0], lane, gh[1], gl[1], c2);
        gelu16(c2);

        // ---- store: stage through per-wave LDS tile, then write FULL
        // 128B lines (8 lanes x 16B per site) to kill partial-sector RMW ----
        // register layout: lane holds site n, feats {4*half + 8q + e}.
#pragma unroll
        for (int q = 0; q < 4; ++q) {
            *(float4*)(lw + n * OTS + q * 8 + 4 * half) =
                make_float4(c2[4*q+0], c2[4*q+1], c2[4*q+2], c2[4*q+3]);
        }
        // within-wave LDS write->read: drain LDS queue, fence compiler reorder
        asm volatile("s_waitcnt lgkmcnt(0)" ::: "memory");
        __builtin_amdgcn_sched_barrier(0);
#pragma unroll
        for (int it = 0; it < 4; ++it) {
            const int sl    = it * 8 + s_lo;           // site-local 0..31
            const int gsite = g * 32 + sl;
            float4 v = *(const float4*)(lw + sl * OTS + cpos * 4);
            *(float4*)(out + ((size_t)gsite * Fd + f) * 32 + cpos * 4) = v;
        }
    }
}

} // anonymous namespace

extern "C" void kernel_launch(void* const* d_in, const int* in_sizes, int n_in,
                              void* d_out, int out_size, void* d_ws, size_t ws_size,
                              hipStream_t stream)
{
    const float* x   = (const float*)d_in[0];
    const float* Wr1 = (const float*)d_in[1];
    const float* br1 = (const float*)d_in[2];
    const float* Wr2 = (const float*)d_in[3];
    const float* br2 = (const float*)d_in[4];
    const float* Wr3 = (const float*)d_in[5];
    const float* br3 = (const float*)d_in[6];
    const float* Wi1 = (const float*)d_in[7];
    const float* bi1 = (const float*)d_in[8];
    const float* Wi2 = (const float*)d_in[9];
    const float* bi2 = (const float*)d_in[10];
    const float* Wi3 = (const float*)d_in[11];
    const float* bi3 = (const float*)d_in[12];
    const float* Wf1 = (const float*)d_in[13];
    const float* bf1 = (const float*)d_in[14];
    const float* Wf2 = (const float*)d_in[15];
    const float* bf2 = (const float*)d_in[16];
    float* out = (float*)d_out;

    dim3 grid(GX, Fd, 1);
    dim3 block(256, 1, 1);
    hipLaunchKernelGGL(dcp_mfma_kernel, grid, block, 0, stream,
                       x, Wr1, br1, Wr2, br2, Wr3, br3,
                       Wi1, bi1, Wi2, bi2, Wi3, bi3,
                       Wf1, bf1, Wf2, bf2, out);
}

// Round 4
// 393.637 us; speedup vs baseline: 1.6423x; 1.0195x over previous
//
#include <hip/hip_runtime.h>

namespace {

constexpr int P   = 361;
constexpr int Fd  = 20;
constexpr int BPc = 256 * P;        // 92416 sites
constexpr int NG  = BPc / 32;       // 2888 site-groups per f
constexpr int GPW = 19;             // groups per wave-stream
constexpr int GX  = (NG / GPW) / 4; // 38 blocks.x (4 waves/block)

constexpr int OTS = 36;             // out-tile row stride in floats (144B, 16B-aligned)

typedef __bf16 bf16x8 __attribute__((ext_vector_type(8)));
typedef __bf16 bf16x2 __attribute__((ext_vector_type(2)));
typedef float  f32x2v __attribute__((ext_vector_type(2)));
typedef float  f32x16 __attribute__((ext_vector_type(16)));

// native <2 x float> fma -> backend selects v_pk_fma_f32 on gfx950
__device__ __forceinline__ f32x2v vfma2(f32x2v a, f32x2v b, f32x2v c) {
    return __builtin_elementwise_fma(a, b, c);
}

// packed-pair GELU (exact erf form, A&S 7.1.26 poly).
// BIT-IDENTICAL per lane to the R2 scalar gelu_f:
//  - q(t) = -poly(t) via negated coefficients (RNE-exact under negation)
//  - erf_abs = fma(q, e2, 1) == fma(-poly, e2, 1)
//  - final (0.5x)*(1+erf), same association as scalar
//  - exp2 arg (u*u)*(-log2e) == ((-u)*u)*log2e bitwise
__device__ __forceinline__ f32x2v gelu2(f32x2v x) {
    const f32x2v csq   = {0.70710678118654752440f, 0.70710678118654752440f};
    const f32x2v ca    = {0.3275911f, 0.3275911f};
    const f32x2v one   = {1.0f, 1.0f};
    const f32x2v c5    = {-1.061405429f, -1.061405429f};
    const f32x2v c4    = { 1.453152027f,  1.453152027f};
    const f32x2v c3    = {-1.421413741f, -1.421413741f};
    const f32x2v c2    = { 0.284496736f,  0.284496736f};
    const f32x2v c1    = {-0.254829592f, -0.254829592f};
    const f32x2v cml2e = {-1.4426950408889634f, -1.4426950408889634f};
    const f32x2v chalf = {0.5f, 0.5f};

    f32x2v u = x * csq;
    f32x2v au;
    au.x = __builtin_fabsf(u.x);
    au.y = __builtin_fabsf(u.y);
    f32x2v dd = vfma2(ca, au, one);
    f32x2v t;
    t.x = __builtin_amdgcn_rcpf(dd.x);
    t.y = __builtin_amdgcn_rcpf(dd.y);
    f32x2v q = vfma2(c5, t, c4);
    q = vfma2(q, t, c3);
    q = vfma2(q, t, c2);
    q = vfma2(q, t, c1);
    q = q * t;
    f32x2v w = (u * u) * cml2e;
    f32x2v e;
    e.x = __builtin_amdgcn_exp2f(w.x);
    e.y = __builtin_amdgcn_exp2f(w.y);
    f32x2v erf_abs = vfma2(q, e, one);
    f32x2v erf;
    erf.x = __builtin_copysignf(erf_abs.x, u.x);
    erf.y = __builtin_copysignf(erf_abs.y, u.y);
    f32x2v hx = x * chalf;
    f32x2v s = one + erf;
    return hx * s;
}

// (v0,v1) -> packed hi-bf16 word + packed lo-bf16 word, RNE, via v_cvt_pk_bf16_f32
__device__ __forceinline__ void split_pk(float v0, float v1, unsigned& hw, unsigned& lw) {
    f32x2v vv = {v0, v1};
    bf16x2 hv = __builtin_convertvector(vv, bf16x2);
    unsigned hp = __builtin_bit_cast(unsigned, hv);
    float r0 = __builtin_bit_cast(float, hp << 16);
    float r1 = __builtin_bit_cast(float, hp & 0xffff0000u);
    f32x2v rv = {v0 - r0, v1 - r1};
    bf16x2 lv = __builtin_convertvector(rv, bf16x2);
    hw = hp;
    lw = __builtin_bit_cast(unsigned, lv);
}

__device__ __forceinline__ bf16x8 as_bf8(uint4 u) {
    return __builtin_bit_cast(bf16x8, u);
}

// 3-MFMA bf16x3 product: acc += A * B with A = (ah+al) from LDS frags,
// B = (bh+bl) in registers. Drops al*bl (~2^-18 rel).
__device__ __forceinline__ f32x16 mfma3(const uint4* lf, int lane,
                                        uint4 bh, uint4 bl, f32x16 acc) {
    bf16x8 ah = as_bf8(lf[lane]);
    bf16x8 al = as_bf8(lf[64 + lane]);
    acc = __builtin_amdgcn_mfma_f32_32x32x16_bf16(ah, as_bf8(bh), acc, 0, 0, 0);
    acc = __builtin_amdgcn_mfma_f32_32x32x16_bf16(ah, as_bf8(bl), acc, 0, 0, 0);
    acc = __builtin_amdgcn_mfma_f32_32x32x16_bf16(al, as_bf8(bh), acc, 0, 0, 0);
    return acc;
}

// read per-lane bias (accumulator init) from LDS: layout [half*16 + q*4 + e]
// holds bias[row = e + 8q + 4*half], matching C/D row = (r&3)+8*(r>>2)+4*half.
__device__ __forceinline__ f32x16 bias_acc(const float* lb, int half) {
    f32x16 a;
    const float4* p = (const float4*)(lb + half * 16);
#pragma unroll
    for (int q = 0; q < 4; ++q) {
        float4 v = p[q];
        a[4*q+0] = v.x; a[4*q+1] = v.y; a[4*q+2] = v.z; a[4*q+3] = v.w;
    }
    return a;
}

__device__ __forceinline__ void gelu16(f32x16& c) {
#pragma unroll
    for (int i = 0; i < 8; ++i) {
        f32x2v p = {c[2*i], c[2*i+1]};
        p = gelu2(p);
        c[2*i] = p.x; c[2*i+1] = p.y;
    }
}

// C/D-layout (32 feats x 32 sites) -> two B-fragments (k=0..15, k=16..31),
// hi+lo bf16. C/D: lane holds col n=lane&31, rows (r&3)+8*(r>>2)+4*half.
// B-frag: lane holds n=lane&31, k=(lane>>5)*8+j.
// The half exchange is exactly v_permlane32_swap:
//   swap(A,B): A' = {A_lo, B_lo}, B' = {A_hi, B_hi}
//   v.x,v.z = swap(d[4c+0], d[4c+2]); v.y,v.w = swap(d[4c+1], d[4c+3]).
__device__ __forceinline__ void transform_cd(const f32x16 c, uint4* H, uint4* L) {
    unsigned hd[8], ld[8];
#pragma unroll
    for (int q = 0; q < 4; ++q) {
        split_pk(c[4*q+0], c[4*q+1], hd[2*q],   ld[2*q]);
        split_pk(c[4*q+2], c[4*q+3], hd[2*q+1], ld[2*q+1]);
    }
#pragma unroll
    for (int pr = 0; pr < 2; ++pr) {
        unsigned* d = pr ? ld : hd;
#pragma unroll
        for (int cix = 0; cix < 2; ++cix) {
            unsigned a0 = d[4*cix+0], b0 = d[4*cix+2];
            unsigned a1 = d[4*cix+1], b1 = d[4*cix+3];
            asm("v_permlane32_swap_b32 %0, %1" : "+v"(a0), "+v"(b0));
            asm("v_permlane32_swap_b32 %0, %1" : "+v"(a1), "+v"(b1));
            uint4 v;
            v.x = a0; v.y = a1; v.z = b0; v.w = b1;
            (pr ? L : H)[cix] = v;
        }
    }
}

__global__ __launch_bounds__(256, 3) void dcp_mfma_kernel(
    const float* __restrict__ x,
    const float* __restrict__ Wr1, const float* __restrict__ br1,
    const float* __restrict__ Wr2, const float* __restrict__ br2,
    const float* __restrict__ Wr3, const float* __restrict__ br3,
    const float* __restrict__ Wi1, const float* __restrict__ bi1,
    const float* __restrict__ Wi2, const float* __restrict__ bi2,
    const float* __restrict__ Wi3, const float* __restrict__ bi3,
    const float* __restrict__ Wf1, const float* __restrict__ bf1,
    const float* __restrict__ Wf2, const float* __restrict__ bf2,
    float* __restrict__ out)
{
    // 12 weight A-chunks x {hi,lo}: frag fi=2*chunk+prec, per-lane uint4.
    __shared__ uint4 lfrag[24][64];
    __shared__ __align__(16) float lbias[6][32];
    __shared__ __align__(16) float l1w[2][2][16];   // [branch][0=w,1=b][k]
    // per-wave out-staging tile: 32 sites x 32 feats, row stride OTS floats
    __shared__ __align__(16) float lout[4][32 * OTS];

    const int f   = blockIdx.y;
    const int tid = threadIdx.x;

    // ---------- setup: stage weight A-fragments (bf16 hi/lo) into LDS ----------
    // A[m][k] = W[f][k0+k][m]; lane l: m=l&31, k=(l>>5)*8+j.
    for (int s = tid; s < 12 * 64; s += 256) {
        const int chunk = s >> 6;
        const int l     = s & 63;
        const int m     = l & 31;
        const int kb    = (l >> 5) * 8;
        const float* base; int k0;
        switch (chunk) {
            case 0:  base = Wr2 + f * 512;  k0 = 0;  break;
            case 1:  base = Wi2 + f * 512;  k0 = 0;  break;
            case 2:  base = Wr3 + f * 1024; k0 = 0;  break;
            case 3:  base = Wr3 + f * 1024; k0 = 16; break;
            case 4:  base = Wi3 + f * 1024; k0 = 0;  break;
            case 5:  base = Wi3 + f * 1024; k0 = 16; break;
            case 6:  base = Wf1 + f * 2048; k0 = 0;  break;
            case 7:  base = Wf1 + f * 2048; k0 = 16; break;
            case 8:  base = Wf1 + f * 2048; k0 = 32; break;
            case 9:  base = Wf1 + f * 2048; k0 = 48; break;
            case 10: base = Wf2 + f * 1024; k0 = 0;  break;
            default: base = Wf2 + f * 1024; k0 = 16; break;
        }
        uint4 hv, lv;
        split_pk(base[(k0 + kb + 0) * 32 + m], base[(k0 + kb + 1) * 32 + m], hv.x, lv.x);
        split_pk(base[(k0 + kb + 2) * 32 + m], base[(k0 + kb + 3) * 32 + m], hv.y, lv.y);
        split_pk(base[(k0 + kb + 4) * 32 + m], base[(k0 + kb + 5) * 32 + m], hv.z, lv.z);
        split_pk(base[(k0 + kb + 6) * 32 + m], base[(k0 + kb + 7) * 32 + m], hv.w, lv.w);
        lfrag[2 * chunk + 0][l] = hv;
        lfrag[2 * chunk + 1][l] = lv;
    }
    // biases, rearranged to C/D reg order per lane-half
    if (tid < 192) {
        const int set = tid >> 5, i = tid & 31;
        const int row = (i & 3) + 8 * ((i >> 2) & 3) + 4 * (i >> 4);
        const float* bp;
        switch (set) {
            case 0: bp = br2; break; case 1: bp = bi2; break;
            case 2: bp = br3; break; case 3: bp = bi3; break;
            case 4: bp = bf1; break; default: bp = bf2; break;
        }
        lbias[set][i] = bp[f * 32 + row];
    }
    // layer-1 params
    if (tid < 64) {
        const int br = tid >> 5, rem = tid & 31, ty = rem >> 4, k = rem & 15;
        const float* p = br ? (ty ? bi1 : Wi1) : (ty ? br1 : Wr1);
        l1w[br][ty][k] = p[f * 16 + k];
    }
    __syncthreads();

    const int lane    = tid & 63;
    const int wv      = tid >> 6;
    const int n       = lane & 31;
    const int half    = lane >> 5;
    const int kb      = half * 8;
    const int wstream = blockIdx.x * 4 + wv;

    float* lw = &lout[wv][0];
    const int s_lo = lane >> 3;   // 0..7: which site of the 8-site store slab
    const int cpos = lane & 7;    // which 16B chunk of the site's 128B line

    for (int t = 0; t < GPW; ++t) {
        const int g    = wstream * GPW + t;
        const int site = g * 32 + n;
        const float2 xv = *(const float2*)(x + ((size_t)site * Fd + f) * 2);

        // ---- L1 (K=1, packed VALU), directly in B-fragment layout ----
        uint4 b1h[2], b1l[2];
#pragma unroll
        for (int br = 0; br < 2; ++br) {
            const float xs = br ? xv.y : xv.x;
            const f32x2v xp = {xs, xs};
            f32x2v h[4];
#pragma unroll
            for (int j = 0; j < 4; ++j) {
                f32x2v wv2 = *(const f32x2v*)&l1w[br][0][kb + 2*j];
                f32x2v bv2 = *(const f32x2v*)&l1w[br][1][kb + 2*j];
                h[j] = gelu2(vfma2(xp, wv2, bv2));
            }
            uint4 hv, lv;
            split_pk(h[0].x, h[0].y, hv.x, lv.x);
            split_pk(h[1].x, h[1].y, hv.y, lv.y);
            split_pk(h[2].x, h[2].y, hv.z, lv.z);
            split_pk(h[3].x, h[3].y, hv.w, lv.w);
            b1h[br] = hv; b1l[br] = lv;
        }

        // ---- L2: 16 -> 32, gelu ----
        f32x16 cr = bias_acc(lbias[0], half);
        f32x16 ci = bias_acc(lbias[1], half);
        cr = mfma3(&lfrag[0][0], lane, b1h[0], b1l[0], cr);
        ci = mfma3(&lfrag[2][0], lane, b1h[1], b1l[1], ci);
        gelu16(cr); gelu16(ci);
        uint4 b2h[2][2], b2l[2][2];
        transform_cd(cr, b2h[0], b2l[0]);
        transform_cd(ci, b2h[1], b2l[1]);

        // ---- L3: 32 -> 32, linear ----
        f32x16 ro = bias_acc(lbias[2], half);
        f32x16 io = bias_acc(lbias[3], half);
        ro = mfma3(&lfrag[4][0],  lane, b2h[0][0], b2l[0][0], ro);
        ro = mfma3(&lfrag[6][0],  lane, b2h[0][1], b2l[0][1], ro);
        io = mfma3(&lfrag[8][0],  lane, b2h[1][0], b2l[1][0], io);
        io = mfma3(&lfrag[10][0], lane, b2h[1][1], b2l[1][1], io);
        uint4 fh[4], fl[4];
        transform_cd(ro, &fh[0], &fl[0]);   // F1 k = 0..31
        transform_cd(io, &fh[2], &fl[2]);   // F1 k = 32..63

        // ---- F1: 64 -> 32, gelu ----
        f32x16 c1 = bias_acc(lbias[4], half);
        c1 = mfma3(&lfrag[12][0], lane, fh[0], fl[0], c1);
        c1 = mfma3(&lfrag[14][0], lane, fh[1], fl[1], c1);
        c1 = mfma3(&lfrag[16][0], lane, fh[2], fl[2], c1);
        c1 = mfma3(&lfrag[18][0], lane, fh[3], fl[3], c1);
        gelu16(c1);
        uint4 gh[2], gl[2];
        transform_cd(c1, gh, gl);

        // ---- F2: 32 -> 32, gelu ----
        f32x16 c2 = bias_acc(lbias[5], half);
        c2 = mfma3(&lfrag[20][0], lane, gh[0], gl[0], c2);
        c2 = mfma3(&lfrag[22][0], lane, gh[1], gl[1], c2);
        gelu16(c2);

        // ---- store: stage through per-wave LDS tile, then write FULL
        // 128B lines (8 lanes x 16B per site) to kill partial-sector RMW ----
        // register layout: lane holds site n, feats {4*half + 8q + e}.
#pragma unroll
        for (int q = 0; q < 4; ++q) {
            *(float4*)(lw + n * OTS + q * 8 + 4 * half) =
                make_float4(c2[4*q+0], c2[4*q+1], c2[4*q+2], c2[4*q+3]);
        }
        // within-wave LDS write->read: drain LDS queue, fence compiler reorder
        asm volatile("s_waitcnt lgkmcnt(0)" ::: "memory");
        __builtin_amdgcn_sched_barrier(0);
#pragma unroll
        for (int it = 0; it < 4; ++it) {
            const int sl    = it * 8 + s_lo;           // site-local 0..31
            const int gsite = g * 32 + sl;
            float4 v = *(const float4*)(lw + sl * OTS + cpos * 4);
            *(float4*)(out + ((size_t)gsite * Fd + f) * 32 + cpos * 4) = v;
        }
    }
}

} // anonymous namespace

extern "C" void kernel_launch(void* const* d_in, const int* in_sizes, int n_in,
                              void* d_out, int out_size, void* d_ws, size_t ws_size,
                              hipStream_t stream)
{
    const float* x   = (const float*)d_in[0];
    const float* Wr1 = (const float*)d_in[1];
    const float* br1 = (const float*)d_in[2];
    const float* Wr2 = (const float*)d_in[3];
    const float* br2 = (const float*)d_in[4];
    const float* Wr3 = (const float*)d_in[5];
    const float* br3 = (const float*)d_in[6];
    const float* Wi1 = (const float*)d_in[7];
    const float* bi1 = (const float*)d_in[8];
    const float* Wi2 = (const float*)d_in[9];
    const float* bi2 = (const float*)d_in[10];
    const float* Wi3 = (const float*)d_in[11];
    const float* bi3 = (const float*)d_in[12];
    const float* Wf1 = (const float*)d_in[13];
    const float* bf1 = (const float*)d_in[14];
    const float* Wf2 = (const float*)d_in[15];
    const float* bf2 = (const float*)d_in[16];
    float* out = (float*)d_out;

    dim3 grid(GX, Fd, 1);
    dim3 block(256, 1, 1);
    hipLaunchKernelGGL(dcp_mfma_kernel, grid, block, 0, stream,
                       x, Wr1, br1, Wr2, br2, Wr3, br3,
                       Wi1, bi1, Wi2, bi2, Wi3, bi3,
                       Wf1, bf1, Wf2, bf2, out);
}

// Round 5
// 344.562 us; speedup vs baseline: 1.8762x; 1.1424x over previous
//
#include <hip/hip_runtime.h>

namespace {

constexpr int P   = 361;
constexpr int Fd  = 20;
constexpr int BPc = 256 * P;        // 92416 sites
constexpr int NG  = BPc / 32;       // 2888 site-groups per f
constexpr int GPW = 19;             // groups per wave-stream
constexpr int GX  = (NG / GPW) / 4; // 38 blocks.x (4 waves/block)

constexpr int OTS = 36;             // out-tile row stride in floats (144B, 16B-aligned)

typedef __bf16 bf16x8 __attribute__((ext_vector_type(8)));
typedef __bf16 bf16x2 __attribute__((ext_vector_type(2)));
typedef float  f32x2v __attribute__((ext_vector_type(2)));
typedef float  f32x16 __attribute__((ext_vector_type(16)));

// native <2 x float> fma (correct whether or not backend packs it)
__device__ __forceinline__ f32x2v vfma2(f32x2v a, f32x2v b, f32x2v c) {
    return __builtin_elementwise_fma(a, b, c);
}

// tanh-form GELU: 0.5x(1+tanh(0.79788456(x+0.044715x^3)))
//   y  = x*(c0 + c0c1*x^2)
//   r  = 1/(exp2(2*log2e*y) + 1)        (= 0.5*(1-tanh(y)))
//   g  = x*(1-r) = fma(-x, r, x)
// Saturates exactly: exp2->inf => r=0 => g=x ; exp2->0 => r=1 => g=0.
// 8 VALU ops (2 trans) vs ~15 for the exact-erf form; |err| <= ~3e-4.
__device__ __forceinline__ f32x2v gelu2(f32x2v x) {
    const f32x2v k1  = {0.03567740814183590f, 0.03567740814183590f}; // c0*c1
    const f32x2v k0  = {0.79788456080286536f, 0.79788456080286536f}; // c0
    const f32x2v k2  = {2.88539008177792681f, 2.88539008177792681f}; // 2*log2(e)
    const f32x2v one = {1.0f, 1.0f};
    f32x2v x2 = x * x;
    f32x2v p  = vfma2(x2, k1, k0);
    f32x2v y  = x * p;
    f32x2v w  = y * k2;
    f32x2v e;
    e.x = __builtin_amdgcn_exp2f(w.x);
    e.y = __builtin_amdgcn_exp2f(w.y);
    f32x2v d = e + one;
    f32x2v r;
    r.x = __builtin_amdgcn_rcpf(d.x);
    r.y = __builtin_amdgcn_rcpf(d.y);
    return vfma2(-x, r, x);
}

// (v0,v1) -> packed hi-bf16 word + packed lo-bf16 word, RNE, via v_cvt_pk_bf16_f32
__device__ __forceinline__ void split_pk(float v0, float v1, unsigned& hw, unsigned& lw) {
    f32x2v vv = {v0, v1};
    bf16x2 hv = __builtin_convertvector(vv, bf16x2);
    unsigned hp = __builtin_bit_cast(unsigned, hv);
    float r0 = __builtin_bit_cast(float, hp << 16);
    float r1 = __builtin_bit_cast(float, hp & 0xffff0000u);
    f32x2v rv = {v0 - r0, v1 - r1};
    bf16x2 lv = __builtin_convertvector(rv, bf16x2);
    hw = hp;
    lw = __builtin_bit_cast(unsigned, lv);
}

__device__ __forceinline__ bf16x8 as_bf8(uint4 u) {
    return __builtin_bit_cast(bf16x8, u);
}

// 3-MFMA bf16x3 product: acc += A * B with A = (ah+al) from LDS frags,
// B = (bh+bl) in registers. Drops al*bl (~2^-18 rel).
__device__ __forceinline__ f32x16 mfma3(const uint4* lf, int lane,
                                        uint4 bh, uint4 bl, f32x16 acc) {
    bf16x8 ah = as_bf8(lf[lane]);
    bf16x8 al = as_bf8(lf[64 + lane]);
    acc = __builtin_amdgcn_mfma_f32_32x32x16_bf16(ah, as_bf8(bh), acc, 0, 0, 0);
    acc = __builtin_amdgcn_mfma_f32_32x32x16_bf16(ah, as_bf8(bl), acc, 0, 0, 0);
    acc = __builtin_amdgcn_mfma_f32_32x32x16_bf16(al, as_bf8(bh), acc, 0, 0, 0);
    return acc;
}

// read per-lane bias (accumulator init) from LDS: layout [half*16 + q*4 + e]
// holds bias[row = e + 8q + 4*half], matching C/D row = (r&3)+8*(r>>2)+4*half.
__device__ __forceinline__ f32x16 bias_acc(const float* lb, int half) {
    f32x16 a;
    const float4* p = (const float4*)(lb + half * 16);
#pragma unroll
    for (int q = 0; q < 4; ++q) {
        float4 v = p[q];
        a[4*q+0] = v.x; a[4*q+1] = v.y; a[4*q+2] = v.z; a[4*q+3] = v.w;
    }
    return a;
}

__device__ __forceinline__ void gelu16(f32x16& c) {
#pragma unroll
    for (int i = 0; i < 8; ++i) {
        f32x2v p = {c[2*i], c[2*i+1]};
        p = gelu2(p);
        c[2*i] = p.x; c[2*i+1] = p.y;
    }
}

// C/D-layout (32 feats x 32 sites) -> two B-fragments (k=0..15, k=16..31),
// hi+lo bf16. C/D: lane holds col n=lane&31, rows (r&3)+8*(r>>2)+4*half.
// B-frag: lane holds n=lane&31, k=(lane>>5)*8+j.
// The half exchange is exactly v_permlane32_swap:
//   swap(A,B): A' = {A_lo, B_lo}, B' = {A_hi, B_hi}
//   v.x,v.z = swap(d[4c+0], d[4c+2]); v.y,v.w = swap(d[4c+1], d[4c+3]).
__device__ __forceinline__ void transform_cd(const f32x16 c, uint4* H, uint4* L) {
    unsigned hd[8], ld[8];
#pragma unroll
    for (int q = 0; q < 4; ++q) {
        split_pk(c[4*q+0], c[4*q+1], hd[2*q],   ld[2*q]);
        split_pk(c[4*q+2], c[4*q+3], hd[2*q+1], ld[2*q+1]);
    }
#pragma unroll
    for (int pr = 0; pr < 2; ++pr) {
        unsigned* d = pr ? ld : hd;
#pragma unroll
        for (int cix = 0; cix < 2; ++cix) {
            unsigned a0 = d[4*cix+0], b0 = d[4*cix+2];
            unsigned a1 = d[4*cix+1], b1 = d[4*cix+3];
            asm("v_permlane32_swap_b32 %0, %1" : "+v"(a0), "+v"(b0));
            asm("v_permlane32_swap_b32 %0, %1" : "+v"(a1), "+v"(b1));
            uint4 v;
            v.x = a0; v.y = a1; v.z = b0; v.w = b1;
            (pr ? L : H)[cix] = v;
        }
    }
}

__global__ __launch_bounds__(256, 3) void dcp_mfma_kernel(
    const float* __restrict__ x,
    const float* __restrict__ Wr1, const float* __restrict__ br1,
    const float* __restrict__ Wr2, const float* __restrict__ br2,
    const float* __restrict__ Wr3, const float* __restrict__ br3,
    const float* __restrict__ Wi1, const float* __restrict__ bi1,
    const float* __restrict__ Wi2, const float* __restrict__ bi2,
    const float* __restrict__ Wi3, const float* __restrict__ bi3,
    const float* __restrict__ Wf1, const float* __restrict__ bf1,
    const float* __restrict__ Wf2, const float* __restrict__ bf2,
    float* __restrict__ out)
{
    // 12 weight A-chunks x {hi,lo}: frag fi=2*chunk+prec, per-lane uint4.
    __shared__ uint4 lfrag[24][64];
    __shared__ __align__(16) float lbias[6][32];
    __shared__ __align__(16) float l1w[2][2][16];   // [branch][0=w,1=b][k]
    // per-wave out-staging tile: 32 sites x 32 feats, row stride OTS floats
    __shared__ __align__(16) float lout[4][32 * OTS];

    const int f   = blockIdx.y;
    const int tid = threadIdx.x;

    // ---------- setup: stage weight A-fragments (bf16 hi/lo) into LDS ----------
    // A[m][k] = W[f][k0+k][m]; lane l: m=l&31, k=(l>>5)*8+j.
    for (int s = tid; s < 12 * 64; s += 256) {
        const int chunk = s >> 6;
        const int l     = s & 63;
        const int m     = l & 31;
        const int kb    = (l >> 5) * 8;
        const float* base; int k0;
        switch (chunk) {
            case 0:  base = Wr2 + f * 512;  k0 = 0;  break;
            case 1:  base = Wi2 + f * 512;  k0 = 0;  break;
            case 2:  base = Wr3 + f * 1024; k0 = 0;  break;
            case 3:  base = Wr3 + f * 1024; k0 = 16; break;
            case 4:  base = Wi3 + f * 1024; k0 = 0;  break;
            case 5:  base = Wi3 + f * 1024; k0 = 16; break;
            case 6:  base = Wf1 + f * 2048; k0 = 0;  break;
            case 7:  base = Wf1 + f * 2048; k0 = 16; break;
            case 8:  base = Wf1 + f * 2048; k0 = 32; break;
            case 9:  base = Wf1 + f * 2048; k0 = 48; break;
            case 10: base = Wf2 + f * 1024; k0 = 0;  break;
            default: base = Wf2 + f * 1024; k0 = 16; break;
        }
        uint4 hv, lv;
        split_pk(base[(k0 + kb + 0) * 32 + m], base[(k0 + kb + 1) * 32 + m], hv.x, lv.x);
        split_pk(base[(k0 + kb + 2) * 32 + m], base[(k0 + kb + 3) * 32 + m], hv.y, lv.y);
        split_pk(base[(k0 + kb + 4) * 32 + m], base[(k0 + kb + 5) * 32 + m], hv.z, lv.z);
        split_pk(base[(k0 + kb + 6) * 32 + m], base[(k0 + kb + 7) * 32 + m], hv.w, lv.w);
        lfrag[2 * chunk + 0][l] = hv;
        lfrag[2 * chunk + 1][l] = lv;
    }
    // biases, rearranged to C/D reg order per lane-half
    if (tid < 192) {
        const int set = tid >> 5, i = tid & 31;
        const int row = (i & 3) + 8 * ((i >> 2) & 3) + 4 * (i >> 4);
        const float* bp;
        switch (set) {
            case 0: bp = br2; break; case 1: bp = bi2; break;
            case 2: bp = br3; break; case 3: bp = bi3; break;
            case 4: bp = bf1; break; default: bp = bf2; break;
        }
        lbias[set][i] = bp[f * 32 + row];
    }
    // layer-1 params
    if (tid < 64) {
        const int br = tid >> 5, rem = tid & 31, ty = rem >> 4, k = rem & 15;
        const float* p = br ? (ty ? bi1 : Wi1) : (ty ? br1 : Wr1);
        l1w[br][ty][k] = p[f * 16 + k];
    }
    __syncthreads();

    const int lane    = tid & 63;
    const int wv      = tid >> 6;
    const int n       = lane & 31;
    const int half    = lane >> 5;
    const int kb      = half * 8;
    const int wstream = blockIdx.x * 4 + wv;

    float* lw = &lout[wv][0];
    const int s_lo = lane >> 3;   // 0..7: which site of the 8-site store slab
    const int cpos = lane & 7;    // which 16B chunk of the site's 128B line

    for (int t = 0; t < GPW; ++t) {
        const int g    = wstream * GPW + t;
        const int site = g * 32 + n;
        const float2 xv = *(const float2*)(x + ((size_t)site * Fd + f) * 2);

        // ---- L1 (K=1, on VALU), directly in B-fragment layout ----
        uint4 b1h[2], b1l[2];
#pragma unroll
        for (int br = 0; br < 2; ++br) {
            const float xs = br ? xv.y : xv.x;
            const f32x2v xp = {xs, xs};
            f32x2v h[4];
#pragma unroll
            for (int j = 0; j < 4; ++j) {
                f32x2v wv2 = *(const f32x2v*)&l1w[br][0][kb + 2*j];
                f32x2v bv2 = *(const f32x2v*)&l1w[br][1][kb + 2*j];
                h[j] = gelu2(vfma2(xp, wv2, bv2));
            }
            uint4 hv, lv;
            split_pk(h[0].x, h[0].y, hv.x, lv.x);
            split_pk(h[1].x, h[1].y, hv.y, lv.y);
            split_pk(h[2].x, h[2].y, hv.z, lv.z);
            split_pk(h[3].x, h[3].y, hv.w, lv.w);
            b1h[br] = hv; b1l[br] = lv;
        }

        // ---- L2: 16 -> 32, gelu ----
        f32x16 cr = bias_acc(lbias[0], half);
        f32x16 ci = bias_acc(lbias[1], half);
        cr = mfma3(&lfrag[0][0], lane, b1h[0], b1l[0], cr);
        ci = mfma3(&lfrag[2][0], lane, b1h[1], b1l[1], ci);
        gelu16(cr); gelu16(ci);
        uint4 b2h[2][2], b2l[2][2];
        transform_cd(cr, b2h[0], b2l[0]);
        transform_cd(ci, b2h[1], b2l[1]);

        // ---- L3: 32 -> 32, linear ----
        f32x16 ro = bias_acc(lbias[2], half);
        f32x16 io = bias_acc(lbias[3], half);
        ro = mfma3(&lfrag[4][0],  lane, b2h[0][0], b2l[0][0], ro);
        ro = mfma3(&lfrag[6][0],  lane, b2h[0][1], b2l[0][1], ro);
        io = mfma3(&lfrag[8][0],  lane, b2h[1][0], b2l[1][0], io);
        io = mfma3(&lfrag[10][0], lane, b2h[1][1], b2l[1][1], io);
        uint4 fh[4], fl[4];
        transform_cd(ro, &fh[0], &fl[0]);   // F1 k = 0..31
        transform_cd(io, &fh[2], &fl[2]);   // F1 k = 32..63

        // ---- F1: 64 -> 32, gelu ----
        f32x16 c1 = bias_acc(lbias[4], half);
        c1 = mfma3(&lfrag[12][0], lane, fh[0], fl[0], c1);
        c1 = mfma3(&lfrag[14][0], lane, fh[1], fl[1], c1);
        c1 = mfma3(&lfrag[16][0], lane, fh[2], fl[2], c1);
        c1 = mfma3(&lfrag[18][0], lane, fh[3], fl[3], c1);
        gelu16(c1);
        uint4 gh[2], gl[2];
        transform_cd(c1, gh, gl);

        // ---- F2: 32 -> 32, gelu ----
        f32x16 c2 = bias_acc(lbias[5], half);
        c2 = mfma3(&lfrag[20][0], lane, gh[0], gl[0], c2);
        c2 = mfma3(&lfrag[22][0], lane, gh[1], gl[1], c2);
        gelu16(c2);

        // ---- store: stage through per-wave LDS tile, then write FULL
        // 128B lines (8 lanes x 16B per site) to kill partial-sector RMW ----
        // register layout: lane holds site n, feats {4*half + 8q + e}.
#pragma unroll
        for (int q = 0; q < 4; ++q) {
            *(float4*)(lw + n * OTS + q * 8 + 4 * half) =
                make_float4(c2[4*q+0], c2[4*q+1], c2[4*q+2], c2[4*q+3]);
        }
        // within-wave LDS write->read: drain LDS queue, fence compiler reorder
        asm volatile("s_waitcnt lgkmcnt(0)" ::: "memory");
        __builtin_amdgcn_sched_barrier(0);
#pragma unroll
        for (int it = 0; it < 4; ++it) {
            const int sl    = it * 8 + s_lo;           // site-local 0..31
            const int gsite = g * 32 + sl;
            float4 v = *(const float4*)(lw + sl * OTS + cpos * 4);
            *(float4*)(out + ((size_t)gsite * Fd + f) * 32 + cpos * 4) = v;
        }
    }
}

} // anonymous namespace

extern "C" void kernel_launch(void* const* d_in, const int* in_sizes, int n_in,
                              void* d_out, int out_size, void* d_ws, size_t ws_size,
                              hipStream_t stream)
{
    const float* x   = (const float*)d_in[0];
    const float* Wr1 = (const float*)d_in[1];
    const float* br1 = (const float*)d_in[2];
    const float* Wr2 = (const float*)d_in[3];
    const float* br2 = (const float*)d_in[4];
    const float* Wr3 = (const float*)d_in[5];
    const float* br3 = (const float*)d_in[6];
    const float* Wi1 = (const float*)d_in[7];
    const float* bi1 = (const float*)d_in[8];
    const float* Wi2 = (const float*)d_in[9];
    const float* bi2 = (const float*)d_in[10];
    const float* Wi3 = (const float*)d_in[11];
    const float* bi3 = (const float*)d_in[12];
    const float* Wf1 = (const float*)d_in[13];
    const float* bf1 = (const float*)d_in[14];
    const float* Wf2 = (const float*)d_in[15];
    const float* bf2 = (const float*)d_in[16];
    float* out = (float*)d_out;

    dim3 grid(GX, Fd, 1);
    dim3 block(256, 1, 1);
    hipLaunchKernelGGL(dcp_mfma_kernel, grid, block, 0, stream,
                       x, Wr1, br1, Wr2, br2, Wr3, br3,
                       Wi1, bi1, Wi2, bi2, Wi3, bi3,
                       Wf1, bf1, Wf2, bf2, out);
}